// Round 14
// baseline (55.974 us; speedup 1.0000x reference)
//
#include <hip/hip_runtime.h>
#include <hip/hip_bf16.h>

// Winograd F(2x2,3x3) via bf16 MFMA.
// x (8,64,128,128) f32, filt (64,64,3,3) f32 -> Y (8,64,126,126) f32
// Block = (n, kq: 16 k, ONE tt row, uu-half: 32 tiles, all 64 c). 256 thr = 4 waves.
// Grid 4032 = 8 n x 4 kq x 63 tt x 2 uuh; blockIdx&7 = n -> image pinned to one XCD.
// 4 passes (rolled): 2 ch(32c) x 2 a-pairs; 8 ab-planes -> LDS 18.4 KB
// -> 8 blocks/CU co-resident (32 waves = HW cap) with VGPR <= 64.
// No min-waves bound (R10/R11: coercion -> spill).

#define T_TILES 63
#define HW 128
#define OW 126

typedef __attribute__((ext_vector_type(8))) short short8;   // 8 bf16
typedef __attribute__((ext_vector_type(4))) float f32x4;

static __device__ __forceinline__ unsigned int f2bf(float f) {
    unsigned int u = __float_as_uint(f);
    return (u + 0x7FFFu + ((u >> 16) & 1u)) >> 16;   // RNE bf16
}

static __device__ __forceinline__ unsigned int pkbf2(float lo, float hi) {
    __hip_bfloat162 t;
    t.x = __float2bfloat16(lo);
    t.y = __float2bfloat16(hi);
    unsigned int r;
    __builtin_memcpy(&r, &t, 4);
    return r;                                   // v_cvt_pk_bf16_f32
}

// U_frag layout (unchanged): frag[(ab*2+ch)*4+kq][lane 0..63][j 0..7] bf16 (128 KB)
// B-operand lane l holds B[c'=(l>>4)*8+j (+32*ch)][k=(l&15)+16*kq]
__global__ __launch_bounds__(256)
void filter_transform(const float* __restrict__ g, unsigned short* __restrict__ Uf) {
    int idx = blockIdx.x * 256 + threadIdx.x;   // k*64 + c
    if (idx >= 64 * 64) return;
    int k = idx >> 6, c = idx & 63;
    const float* gp = g + idx * 9;
    float g00 = gp[0], g01 = gp[1], g02 = gp[2];
    float g10 = gp[3], g11 = gp[4], g12 = gp[5];
    float g20 = gp[6], g21 = gp[7], g22 = gp[8];
    float w[4][3];
    w[0][0] = g00;                w[0][1] = g01;                w[0][2] = g02;
    w[1][0] = 0.5f*(g00+g10+g20); w[1][1] = 0.5f*(g01+g11+g21); w[1][2] = 0.5f*(g02+g12+g22);
    w[2][0] = 0.5f*(g00-g10+g20); w[2][1] = 0.5f*(g01-g11+g21); w[2][2] = 0.5f*(g02-g12+g22);
    w[3][0] = g20;                w[3][1] = g21;                w[3][2] = g22;

    int kq = k >> 4, kl = k & 15;
    int ch = c >> 5;
    int lane = kl + (((c & 31) >> 3) << 4);
    int j = c & 7;
    #pragma unroll
    for (int a = 0; a < 4; ++a) {
        float uv[4];
        uv[0] = w[a][0];
        uv[1] = 0.5f * (w[a][0] + w[a][1] + w[a][2]);
        uv[2] = 0.5f * (w[a][0] - w[a][1] + w[a][2]);
        uv[3] = w[a][2];
        #pragma unroll
        for (int b = 0; b < 4; ++b) {
            int ab = a * 4 + b;
            size_t off = ((size_t)((ab * 2 + ch) * 4 + kq) * 64 + lane) * 8 + j;
            Uf[off] = (unsigned short)f2bf(uv[b]);
        }
    }
}

#define VSTRIDE 72                    // bytes per tm row (64 data + 8 pad)
#define VPLANE  (32 * VSTRIDE)        // 2304 B per ab-plane; 8 planes = 18432 B
#define YPLANE  132                   // f32 words per k-plane in staging (2x66)

__global__ __launch_bounds__(256)
void winograd_main(const float* __restrict__ x, const unsigned short* __restrict__ Uf,
                   float* __restrict__ Y) {
    __shared__ __align__(16) char smem[8 * VPLANE];   // 18432 B

    const int tid  = threadIdx.x;
    const int lane = tid & 63;
    const int wv   = tid >> 6;                 // 0..3

    const int n   = blockIdx.x & 7;            // XCD pin
    const int r2  = blockIdx.x >> 3;           // 0..503
    const int kq  = r2 & 3;
    const int r3  = r2 >> 2;                   // 0..125
    const int uuh = r3 & 1;
    const int tb  = r3 >> 1;                   // 0..62 (tt row)

    const int mt = wv >> 1;                    // 0..1 M-tile (16 uu each)
    const int ai = wv & 1;                     // a within the active pair

    const int kl = lane & 15;
    const int g4 = lane >> 4;

    f32x4 Yp[2][2];                             // [p][q]
    #pragma unroll
    for (int p = 0; p < 2; ++p)
        #pragma unroll
        for (int q = 0; q < 2; ++q)
            Yp[p][q] = (f32x4){0.f, 0.f, 0.f, 0.f};

    // transform mapping: tm_loc = local uu tile (0..31), cg = c-group of 4.
    // uu_g==63 is padding: clamp address to tile 0; result lands in discarded row.
    const int tm_loc = tid & 31;
    const int cg     = tid >> 5;               // 0..7
    const int uu_g   = uuh * 32 + tm_loc;
    const int tmcg   = (uu_g < T_TILES) ? uu_g : 0;

    // A-fragment read base (within an ab plane)
    const int tmA   = mt * 16 + kl;            // 0..31
    const int abyte = tmA * VSTRIDE + g4 * 16;

    const short8* UfV = (const short8*)Uf;

    #pragma unroll 1
    for (int pass = 0; pass < 4; ++pass) {
        const int ch = pass >> 1;
        const int P  = pass & 1;                // a-pair: a in {2P, 2P+1}
        const int xrow0 = 2 * tb + P;           // rows xrow0..xrow0+2 (max 127)

        // ---- transform: 8 ab planes, 32 tm x 32 c' (4 c/thread) ----
        #pragma unroll
        for (int hp = 0; hp < 2; ++hp) {
            float vv[2][8];
            #pragma unroll
            for (int hh = 0; hh < 2; ++hh) {
                const int c = ch * 32 + cg * 4 + hp * 2 + hh;
                const float* xp = x + (((size_t)(n * 64 + c)) * HW + xrow0) * HW + 2 * tmcg;
                float ld[3][4];
                #pragma unroll
                for (int rr = 0; rr < 3; ++rr) {
                    float2 lo = *reinterpret_cast<const float2*>(xp + rr * HW);
                    float2 hi = *reinterpret_cast<const float2*>(xp + rr * HW + 2);
                    ld[rr][0] = lo.x; ld[rr][1] = lo.y;
                    ld[rr][2] = hi.x; ld[rr][3] = hi.y;
                }
                float wa[2][4];
                #pragma unroll
                for (int j = 0; j < 4; ++j) {
                    if (P == 0) {
                        wa[0][j] = ld[0][j] - ld[2][j];   // a=0
                        wa[1][j] = ld[1][j] + ld[2][j];   // a=1
                    } else {
                        wa[0][j] = ld[1][j] - ld[0][j];   // a=2
                        wa[1][j] = ld[0][j] - ld[2][j];   // a=3
                    }
                }
                #pragma unroll
                for (int al = 0; al < 2; ++al) {
                    vv[hh][al*4+0] = wa[al][0] - wa[al][2];
                    vv[hh][al*4+1] = wa[al][1] + wa[al][2];
                    vv[hh][al*4+2] = wa[al][2] - wa[al][1];
                    vv[hh][al*4+3] = wa[al][1] - wa[al][3];
                }
            }
            const int wb = tm_loc * VSTRIDE + cg * 8 + hp * 4;
            #pragma unroll
            for (int e = 0; e < 8; ++e)
                *reinterpret_cast<unsigned int*>(smem + e * VPLANE + wb) =
                    pkbf2(vv[0][e], vv[1][e]);
        }
        __syncthreads();

        // ---- GEMM: wave (mt, ai): a = 2P+ai, 4 b, 16 k ----
        const int a = 2 * P + ai;
        f32x4 acc[4];
        #pragma unroll
        for (int b = 0; b < 4; ++b) acc[b] = (f32x4){0.f, 0.f, 0.f, 0.f};
        #pragma unroll
        for (int b = 0; b < 4; ++b) {
            const char* ap = smem + (ai * 4 + b) * VPLANE + abyte;
            uint2 q0 = *reinterpret_cast<const uint2*>(ap);
            uint2 q1 = *reinterpret_cast<const uint2*>(ap + 8);
            uint4 t; t.x = q0.x; t.y = q0.y; t.z = q1.x; t.w = q1.y;
            short8 Af = *reinterpret_cast<short8*>(&t);
            short8 Bf = UfV[(size_t)(((a * 4 + b) * 2 + ch) * 4 + kq) * 64 + lane];
            acc[b] = __builtin_amdgcn_mfma_f32_16x16x32_bf16(Af, Bf, acc[b], 0, 0, 0);
        }

        // ---- fold (linear in partial sums) ----
        f32x4 t0 = acc[0] + acc[1] + acc[2];
        f32x4 t1 = acc[1] - acc[2] - acc[3];
        if (a == 0) { Yp[0][0] += t0; Yp[0][1] += t1; }
        if (a == 1) { Yp[0][0] += t0; Yp[0][1] += t1;
                      Yp[1][0] += t0; Yp[1][1] += t1; }
        if (a == 2) { Yp[0][0] += t0; Yp[0][1] += t1;
                      Yp[1][0] -= t0; Yp[1][1] -= t1; }
        if (a == 3) { Yp[1][0] -= t0; Yp[1][1] -= t1; }
        __syncthreads();
    }

    // ---- store: merge ai halves in LDS (16 planes x 2 rows x 64 cols), then
    //      contiguous copy-out (256 B chunks; uuh siblings same XCD -> L2 merge) ----
    float* Ys = reinterpret_cast<float*>(smem);
    if (ai == 0) {
        #pragma unroll
        for (int r = 0; r < 4; ++r) {
            const int uu_loc = mt * 16 + 4 * g4 + r;     // 0..31
            if (uuh * 32 + uu_loc < T_TILES) {
                #pragma unroll
                for (int p = 0; p < 2; ++p)
                    *reinterpret_cast<float2*>(Ys + kl * YPLANE + p * 66 + 2 * uu_loc)
                        = make_float2(Yp[p][0][r], Yp[p][1][r]);
            }
        }
    }
    __syncthreads();
    if (ai == 1) {
        #pragma unroll
        for (int r = 0; r < 4; ++r) {
            const int uu_loc = mt * 16 + 4 * g4 + r;
            if (uuh * 32 + uu_loc < T_TILES) {
                #pragma unroll
                for (int p = 0; p < 2; ++p) {
                    float2* ptr = reinterpret_cast<float2*>(
                        Ys + kl * YPLANE + p * 66 + 2 * uu_loc);
                    float2 v = *ptr;
                    v.x += Yp[p][0][r];
                    v.y += Yp[p][1][r];
                    *ptr = v;
                }
            }
        }
    }
    __syncthreads();

    // copy out: 16 planes x 2 rows x 32 float2 = 1024 units / 256 thr = 4 each
    #pragma unroll
    for (int j = 0; j < 4; ++j) {
        const int unit  = tid + 256 * j;
        const int plane = unit >> 6;            // 0..15
        const int sub   = unit & 63;
        const int row   = sub >> 5;             // 0..1
        const int i2    = sub & 31;             // float2 index within 64-col chunk
        const int col_g = uuh * 64 + 2 * i2;
        if (col_g < 125) {                      // float2 covers col_g, col_g+1
            float2 v = *reinterpret_cast<const float2*>(
                Ys + plane * YPLANE + row * 66 + 2 * i2);
            *reinterpret_cast<float2*>(
                Y + ((size_t)(n * 64 + kq * 16 + plane)) * (OW * OW)
                  + (size_t)(2 * tb + row) * OW + col_g) = v;
        }
    }
}

extern "C" void kernel_launch(void* const* d_in, const int* in_sizes, int n_in,
                              void* d_out, int out_size, void* d_ws, size_t ws_size,
                              hipStream_t stream) {
    const float* x    = (const float*)d_in[0];
    const float* filt = (const float*)d_in[1];
    float* Y = (float*)d_out;
    unsigned short* Uf = (unsigned short*)d_ws;    // 128 KB bf16 U fragments

    filter_transform<<<16, 256, 0, stream>>>(filt, Uf);

    winograd_main<<<dim3(4032), 256, 0, stream>>>(x, Uf, Y);
}

// Round 15
// 53.952 us; speedup vs baseline: 1.0375x; 1.0375x over previous
//
#include <hip/hip_runtime.h>
#include <hip/hip_bf16.h>

// Winograd F(2x2,3x3) via bf16 MFMA.
// x (8,64,128,128) f32, filt (64,64,3,3) f32 -> Y (8,64,126,126) f32
// Block = (n, kh: 32 k, ONE tt row, all 63 uu, all 64 c). 512 thr = 8 waves.
// Grid 1008 = 8 n x 2 kh x 63 tt; blockIdx&7 = n -> image pinned to one XCD.
// 4 passes (rolled): 2 ch(32c) x 2 a-pairs; 8 ab-planes/pass -> LDS 36.9 KB.
// vs R13 (kq quarters): transform per block identical but feeds 2x the k ->
// total transform VALU halves; GEMM = 8 MFMA/wave/pass (kq2 loop, Af reused).
// No min-waves bound (R10/R11: coercion -> spill).

#define T_TILES 63
#define HW 128
#define OW 126

typedef __attribute__((ext_vector_type(8))) short short8;   // 8 bf16
typedef __attribute__((ext_vector_type(4))) float f32x4;

static __device__ __forceinline__ unsigned int f2bf(float f) {
    unsigned int u = __float_as_uint(f);
    return (u + 0x7FFFu + ((u >> 16) & 1u)) >> 16;   // RNE bf16
}

static __device__ __forceinline__ unsigned int pkbf2(float lo, float hi) {
    __hip_bfloat162 t;
    t.x = __float2bfloat16(lo);
    t.y = __float2bfloat16(hi);
    unsigned int r;
    __builtin_memcpy(&r, &t, 4);
    return r;                                   // v_cvt_pk_bf16_f32
}

// U_frag layout (unchanged): frag[(ab*2+ch)*4+kq][lane 0..63][j 0..7] bf16 (128 KB)
// B-operand lane l holds B[c'=(l>>4)*8+j (+32*ch)][k=(l&15)+16*kq]
__global__ __launch_bounds__(256)
void filter_transform(const float* __restrict__ g, unsigned short* __restrict__ Uf) {
    int idx = blockIdx.x * 256 + threadIdx.x;   // k*64 + c
    if (idx >= 64 * 64) return;
    int k = idx >> 6, c = idx & 63;
    const float* gp = g + idx * 9;
    float g00 = gp[0], g01 = gp[1], g02 = gp[2];
    float g10 = gp[3], g11 = gp[4], g12 = gp[5];
    float g20 = gp[6], g21 = gp[7], g22 = gp[8];
    float w[4][3];
    w[0][0] = g00;                w[0][1] = g01;                w[0][2] = g02;
    w[1][0] = 0.5f*(g00+g10+g20); w[1][1] = 0.5f*(g01+g11+g21); w[1][2] = 0.5f*(g02+g12+g22);
    w[2][0] = 0.5f*(g00-g10+g20); w[2][1] = 0.5f*(g01-g11+g21); w[2][2] = 0.5f*(g02-g12+g22);
    w[3][0] = g20;                w[3][1] = g21;                w[3][2] = g22;

    int kq = k >> 4, kl = k & 15;
    int ch = c >> 5;
    int lane = kl + (((c & 31) >> 3) << 4);
    int j = c & 7;
    #pragma unroll
    for (int a = 0; a < 4; ++a) {
        float uv[4];
        uv[0] = w[a][0];
        uv[1] = 0.5f * (w[a][0] + w[a][1] + w[a][2]);
        uv[2] = 0.5f * (w[a][0] - w[a][1] + w[a][2]);
        uv[3] = w[a][2];
        #pragma unroll
        for (int b = 0; b < 4; ++b) {
            int ab = a * 4 + b;
            size_t off = ((size_t)((ab * 2 + ch) * 4 + kq) * 64 + lane) * 8 + j;
            Uf[off] = (unsigned short)f2bf(uv[b]);
        }
    }
}

#define VSTRIDE 72                    // bytes per tm row (64 data + 8 pad)
#define VPLANE  (64 * VSTRIDE)        // 4608 B per ab-plane; 8 planes = 36864 B
#define YSTRIDE 254                   // f32 words per k-plane in staging (252 + 2)

__global__ __launch_bounds__(512)
void winograd_main(const float* __restrict__ x, const unsigned short* __restrict__ Uf,
                   float* __restrict__ Y) {
    __shared__ __align__(16) char smem[8 * VPLANE];   // 36864 B

    const int tid  = threadIdx.x;
    const int lane = tid & 63;
    const int wv   = tid >> 6;                 // 0..7

    const int n  = blockIdx.x & 7;             // XCD pin
    const int r2 = blockIdx.x >> 3;            // 0..125
    const int kh = r2 & 1;                     // k half (32 k)
    const int tb = r2 >> 1;                    // 0..62 (tt row)

    const int mt = wv >> 1;                    // 0..3 M-tile (16 uu each)
    const int ai = wv & 1;                     // a within the active pair

    const int kl = lane & 15;
    const int g4 = lane >> 4;

    f32x4 Yp[2][2][2];                          // [kq2][p][q]
    #pragma unroll
    for (int kq2 = 0; kq2 < 2; ++kq2)
        #pragma unroll
        for (int p = 0; p < 2; ++p)
            #pragma unroll
            for (int q = 0; q < 2; ++q)
                Yp[kq2][p][q] = (f32x4){0.f, 0.f, 0.f, 0.f};

    // transform mapping: tm = uu tile (0..63; 63 = pad -> clamp addr, output
    // lands in discarded C row 63), cg = c-group of 4 channels
    const int tm  = lane;
    const int cg  = wv;
    const int tmc = (tm < T_TILES) ? tm : 0;

    // A-fragment read base (within an ab plane)
    const int tmA   = mt * 16 + kl;
    const int abyte = tmA * VSTRIDE + g4 * 16;

    const short8* UfV = (const short8*)Uf;

    #pragma unroll 1
    for (int pass = 0; pass < 4; ++pass) {
        const int ch = pass >> 1;
        const int P  = pass & 1;                // a-pair: a in {2P, 2P+1}
        const int xrow0 = 2 * tb + P;           // rows xrow0..xrow0+2 (max 127)

        // ---- transform: 8 ab planes, 64 tm x 32 c' (4 c/thread) ----
        #pragma unroll
        for (int hp = 0; hp < 2; ++hp) {
            float vv[2][8];
            #pragma unroll
            for (int hh = 0; hh < 2; ++hh) {
                const int c = ch * 32 + cg * 4 + hp * 2 + hh;
                const float* xp = x + (((size_t)(n * 64 + c)) * HW + xrow0) * HW + 2 * tmc;
                float ld[3][4];
                #pragma unroll
                for (int rr = 0; rr < 3; ++rr) {
                    float2 lo = *reinterpret_cast<const float2*>(xp + rr * HW);
                    float2 hi = *reinterpret_cast<const float2*>(xp + rr * HW + 2);
                    ld[rr][0] = lo.x; ld[rr][1] = lo.y;
                    ld[rr][2] = hi.x; ld[rr][3] = hi.y;
                }
                float wa[2][4];
                #pragma unroll
                for (int j = 0; j < 4; ++j) {
                    if (P == 0) {
                        wa[0][j] = ld[0][j] - ld[2][j];   // a=0
                        wa[1][j] = ld[1][j] + ld[2][j];   // a=1
                    } else {
                        wa[0][j] = ld[1][j] - ld[0][j];   // a=2
                        wa[1][j] = ld[0][j] - ld[2][j];   // a=3
                    }
                }
                #pragma unroll
                for (int al = 0; al < 2; ++al) {
                    vv[hh][al*4+0] = wa[al][0] - wa[al][2];
                    vv[hh][al*4+1] = wa[al][1] + wa[al][2];
                    vv[hh][al*4+2] = wa[al][2] - wa[al][1];
                    vv[hh][al*4+3] = wa[al][1] - wa[al][3];
                }
            }
            const int wb = tm * VSTRIDE + cg * 8 + hp * 4;
            #pragma unroll
            for (int e = 0; e < 8; ++e)
                *reinterpret_cast<unsigned int*>(smem + e * VPLANE + wb) =
                    pkbf2(vv[0][e], vv[1][e]);
        }
        __syncthreads();

        // ---- GEMM: wave (mt, ai): a = 2P+ai, 4 b, 32 k (kq2 loop, Af reused) ----
        const int a = 2 * P + ai;
        short8 Af[4];
        #pragma unroll
        for (int b = 0; b < 4; ++b) {
            const char* ap = smem + (ai * 4 + b) * VPLANE + abyte;
            uint2 q0 = *reinterpret_cast<const uint2*>(ap);
            uint2 q1 = *reinterpret_cast<const uint2*>(ap + 8);
            uint4 t; t.x = q0.x; t.y = q0.y; t.z = q1.x; t.w = q1.y;
            Af[b] = *reinterpret_cast<short8*>(&t);
        }
        #pragma unroll
        for (int kq2 = 0; kq2 < 2; ++kq2) {
            const int kq = kh * 2 + kq2;
            f32x4 acc[4];
            #pragma unroll
            for (int b = 0; b < 4; ++b) acc[b] = (f32x4){0.f, 0.f, 0.f, 0.f};
            #pragma unroll
            for (int b = 0; b < 4; ++b) {
                short8 Bf = UfV[(size_t)(((a * 4 + b) * 2 + ch) * 4 + kq) * 64 + lane];
                acc[b] = __builtin_amdgcn_mfma_f32_16x16x32_bf16(Af[b], Bf, acc[b], 0, 0, 0);
            }
            // ---- fold (linear in partial sums) ----
            f32x4 t0 = acc[0] + acc[1] + acc[2];
            f32x4 t1 = acc[1] - acc[2] - acc[3];
            if (a == 0) { Yp[kq2][0][0] += t0; Yp[kq2][0][1] += t1; }
            if (a == 1) { Yp[kq2][0][0] += t0; Yp[kq2][0][1] += t1;
                          Yp[kq2][1][0] += t0; Yp[kq2][1][1] += t1; }
            if (a == 2) { Yp[kq2][0][0] += t0; Yp[kq2][0][1] += t1;
                          Yp[kq2][1][0] -= t0; Yp[kq2][1][1] -= t1; }
            if (a == 3) { Yp[kq2][1][0] -= t0; Yp[kq2][1][1] -= t1; }
        }
        __syncthreads();
    }

    // ---- store: merge ai halves in LDS (32 planes x 2 rows x 126), then
    //      plane-contiguous copy-out (504 B row chunks) ----
    float* Ys = reinterpret_cast<float*>(smem);
    if (ai == 0) {
        #pragma unroll
        for (int kq2 = 0; kq2 < 2; ++kq2) {
            const int plane = kq2 * 16 + kl;
            #pragma unroll
            for (int r = 0; r < 4; ++r) {
                const int uu = mt * 16 + 4 * g4 + r;
                if (uu < T_TILES) {
                    #pragma unroll
                    for (int p = 0; p < 2; ++p)
                        *reinterpret_cast<float2*>(Ys + plane * YSTRIDE + p * 126 + 2 * uu)
                            = make_float2(Yp[kq2][p][0][r], Yp[kq2][p][1][r]);
                }
            }
        }
    }
    __syncthreads();
    if (ai == 1) {
        #pragma unroll
        for (int kq2 = 0; kq2 < 2; ++kq2) {
            const int plane = kq2 * 16 + kl;
            #pragma unroll
            for (int r = 0; r < 4; ++r) {
                const int uu = mt * 16 + 4 * g4 + r;
                if (uu < T_TILES) {
                    #pragma unroll
                    for (int p = 0; p < 2; ++p) {
                        float2* ptr = reinterpret_cast<float2*>(
                            Ys + plane * YSTRIDE + p * 126 + 2 * uu);
                        float2 v = *ptr;
                        v.x += Yp[kq2][p][0][r];
                        v.y += Yp[kq2][p][1][r];
                        *ptr = v;
                    }
                }
            }
        }
    }
    __syncthreads();

    // copy out: 32 planes x 2 rows x 63 float2; 4096 units / 512 thr = 8 each
    #pragma unroll
    for (int i = 0; i < 8; ++i) {
        const int unit  = tid + 512 * i;        // 0..4095
        const int plane = unit >> 7;            // 0..31
        const int sub   = unit & 127;
        const int row   = sub >> 6;             // 0..1
        const int c2    = sub & 63;
        if (c2 < 63) {
            float2 v = *reinterpret_cast<const float2*>(
                Ys + plane * YSTRIDE + row * 126 + 2 * c2);
            *reinterpret_cast<float2*>(
                Y + ((size_t)(n * 64 + kh * 32 + plane)) * (OW * OW)
                  + (size_t)(2 * tb + row) * OW + 2 * c2) = v;
        }
    }
}

extern "C" void kernel_launch(void* const* d_in, const int* in_sizes, int n_in,
                              void* d_out, int out_size, void* d_ws, size_t ws_size,
                              hipStream_t stream) {
    const float* x    = (const float*)d_in[0];
    const float* filt = (const float*)d_in[1];
    float* Y = (float*)d_out;
    unsigned short* Uf = (unsigned short*)d_ws;    // 128 KB bf16 U fragments

    filter_transform<<<16, 256, 0, stream>>>(filt, Uf);

    winograd_main<<<dim3(1008), 512, 0, stream>>>(x, Uf, Y);
}

// Round 16
// 39.078 us; speedup vs baseline: 1.4324x; 1.3806x over previous
//
#include <hip/hip_runtime.h>
#include <hip/hip_bf16.h>

// Winograd F(2x2,3x3) via bf16 MFMA.
// x (8,64,128,128) f32, filt (64,64,3,3) f32 -> Y (8,64,126,126) f32
// Block = (n, kh: 32 k, ONE tt row, all 63 uu, all 64 c). 512 thr = 8 waves.
// Grid 1008 = 8 n x 2 kh x 63 tt; blockIdx&7 = n -> image pinned to one XCD.
// 4 passes: 2 ch(32c) x 2 a-pairs; 8 ab-planes/pass -> LDS 36.9 KB.
// Wave = (mt, kq2): each wave does BOTH a of the pair for ONE k-quarter ->
// Yp = 16 regs (not 32), no Af caching, no ai-merge in epilogue.
// Target: VGPR <= 64 (wave tier! 65+ halves residency -- R15 post-mortem).
// No min-waves bound (R10/R11: coercion -> spill).

#define T_TILES 63
#define HW 128
#define OW 126

typedef __attribute__((ext_vector_type(8))) short short8;   // 8 bf16
typedef __attribute__((ext_vector_type(4))) float f32x4;

static __device__ __forceinline__ unsigned int f2bf(float f) {
    unsigned int u = __float_as_uint(f);
    return (u + 0x7FFFu + ((u >> 16) & 1u)) >> 16;   // RNE bf16
}

static __device__ __forceinline__ unsigned int pkbf2(float lo, float hi) {
    __hip_bfloat162 t;
    t.x = __float2bfloat16(lo);
    t.y = __float2bfloat16(hi);
    unsigned int r;
    __builtin_memcpy(&r, &t, 4);
    return r;                                   // v_cvt_pk_bf16_f32
}

// U_frag layout (unchanged): frag[(ab*2+ch)*4+kq][lane 0..63][j 0..7] bf16 (128 KB)
// B-operand lane l holds B[c'=(l>>4)*8+j (+32*ch)][k=(l&15)+16*kq]
__global__ __launch_bounds__(256)
void filter_transform(const float* __restrict__ g, unsigned short* __restrict__ Uf) {
    int idx = blockIdx.x * 256 + threadIdx.x;   // k*64 + c
    if (idx >= 64 * 64) return;
    int k = idx >> 6, c = idx & 63;
    const float* gp = g + idx * 9;
    float g00 = gp[0], g01 = gp[1], g02 = gp[2];
    float g10 = gp[3], g11 = gp[4], g12 = gp[5];
    float g20 = gp[6], g21 = gp[7], g22 = gp[8];
    float w[4][3];
    w[0][0] = g00;                w[0][1] = g01;                w[0][2] = g02;
    w[1][0] = 0.5f*(g00+g10+g20); w[1][1] = 0.5f*(g01+g11+g21); w[1][2] = 0.5f*(g02+g12+g22);
    w[2][0] = 0.5f*(g00-g10+g20); w[2][1] = 0.5f*(g01-g11+g21); w[2][2] = 0.5f*(g02-g12+g22);
    w[3][0] = g20;                w[3][1] = g21;                w[3][2] = g22;

    int kq = k >> 4, kl = k & 15;
    int ch = c >> 5;
    int lane = kl + (((c & 31) >> 3) << 4);
    int j = c & 7;
    #pragma unroll
    for (int a = 0; a < 4; ++a) {
        float uv[4];
        uv[0] = w[a][0];
        uv[1] = 0.5f * (w[a][0] + w[a][1] + w[a][2]);
        uv[2] = 0.5f * (w[a][0] - w[a][1] + w[a][2]);
        uv[3] = w[a][2];
        #pragma unroll
        for (int b = 0; b < 4; ++b) {
            int ab = a * 4 + b;
            size_t off = ((size_t)((ab * 2 + ch) * 4 + kq) * 64 + lane) * 8 + j;
            Uf[off] = (unsigned short)f2bf(uv[b]);
        }
    }
}

#define VSTRIDE 72                    // bytes per tm row (64 data + 8 pad)
#define VPLANE  (64 * VSTRIDE)        // 4608 B per ab-plane; 8 planes = 36864 B
#define YSTRIDE 254                   // f32 words per k-plane in staging (252 + 2)

__global__ __launch_bounds__(512)
void winograd_main(const float* __restrict__ x, const unsigned short* __restrict__ Uf,
                   float* __restrict__ Y) {
    __shared__ __align__(16) char smem[8 * VPLANE];   // 36864 B

    const int tid  = threadIdx.x;
    const int lane = tid & 63;
    const int wv   = tid >> 6;                 // 0..7

    const int n  = blockIdx.x & 7;             // XCD pin
    const int r2 = blockIdx.x >> 3;            // 0..125
    const int kh = r2 & 1;                     // k half (32 k)
    const int tb = r2 >> 1;                    // 0..62 (tt row)

    const int mt  = wv >> 1;                   // 0..3 M-tile (16 uu each)
    const int kq2 = wv & 1;                    // k-quarter within half
    const int kq  = kh * 2 + kq2;

    const int kl = lane & 15;
    const int g4 = lane >> 4;

    f32x4 Yp[2][2];                             // [p][q] -- 16 VGPRs
    #pragma unroll
    for (int p = 0; p < 2; ++p)
        #pragma unroll
        for (int q = 0; q < 2; ++q)
            Yp[p][q] = (f32x4){0.f, 0.f, 0.f, 0.f};

    // transform mapping: tm = uu tile (0..63; 63 = pad -> clamp addr, output
    // lands in discarded C row 63), cg = c-group of 4 channels
    const int tm  = lane;
    const int cg  = wv;
    const int tmc = (tm < T_TILES) ? tm : 0;

    // A-fragment read base (within an ab plane)
    const int tmA   = mt * 16 + kl;
    const int abyte = tmA * VSTRIDE + g4 * 16;

    const short8* UfV = (const short8*)Uf;

    #pragma unroll 1
    for (int pass = 0; pass < 4; ++pass) {
        const int ch = pass >> 1;
        const int P  = pass & 1;                // a-pair: a in {2P, 2P+1}
        const int xrow0 = 2 * tb + P;           // rows xrow0..xrow0+2 (max 127)

        // ---- transform: 8 ab planes, 64 tm x 32 c' (4 c/thread) ----
        #pragma unroll
        for (int hp = 0; hp < 2; ++hp) {
            float vv[2][8];
            #pragma unroll
            for (int hh = 0; hh < 2; ++hh) {
                const int c = ch * 32 + cg * 4 + hp * 2 + hh;
                const float* xp = x + (((size_t)(n * 64 + c)) * HW + xrow0) * HW + 2 * tmc;
                float ld[3][4];
                #pragma unroll
                for (int rr = 0; rr < 3; ++rr) {
                    float2 lo = *reinterpret_cast<const float2*>(xp + rr * HW);
                    float2 hi = *reinterpret_cast<const float2*>(xp + rr * HW + 2);
                    ld[rr][0] = lo.x; ld[rr][1] = lo.y;
                    ld[rr][2] = hi.x; ld[rr][3] = hi.y;
                }
                float wa[2][4];
                #pragma unroll
                for (int j = 0; j < 4; ++j) {
                    if (P == 0) {
                        wa[0][j] = ld[0][j] - ld[2][j];   // a=0
                        wa[1][j] = ld[1][j] + ld[2][j];   // a=1
                    } else {
                        wa[0][j] = ld[1][j] - ld[0][j];   // a=2
                        wa[1][j] = ld[0][j] - ld[2][j];   // a=3
                    }
                }
                #pragma unroll
                for (int al = 0; al < 2; ++al) {
                    vv[hh][al*4+0] = wa[al][0] - wa[al][2];
                    vv[hh][al*4+1] = wa[al][1] + wa[al][2];
                    vv[hh][al*4+2] = wa[al][2] - wa[al][1];
                    vv[hh][al*4+3] = wa[al][1] - wa[al][3];
                }
            }
            const int wb = tm * VSTRIDE + cg * 8 + hp * 4;
            #pragma unroll
            for (int e = 0; e < 8; ++e)
                *reinterpret_cast<unsigned int*>(smem + e * VPLANE + wb) =
                    pkbf2(vv[0][e], vv[1][e]);
        }
        __syncthreads();

        // ---- GEMM: wave (mt, kq2): BOTH a of the pair, 4 b, 16 k ----
        #pragma unroll
        for (int aa = 0; aa < 2; ++aa) {
            const int a = 2 * P + aa;
            f32x4 acc[4];
            #pragma unroll
            for (int b = 0; b < 4; ++b) acc[b] = (f32x4){0.f, 0.f, 0.f, 0.f};
            #pragma unroll
            for (int b = 0; b < 4; ++b) {
                const char* ap = smem + (aa * 4 + b) * VPLANE + abyte;
                uint2 q0 = *reinterpret_cast<const uint2*>(ap);
                uint2 q1 = *reinterpret_cast<const uint2*>(ap + 8);
                uint4 t; t.x = q0.x; t.y = q0.y; t.z = q1.x; t.w = q1.y;
                short8 Af = *reinterpret_cast<short8*>(&t);
                short8 Bf = UfV[(size_t)(((a * 4 + b) * 2 + ch) * 4 + kq) * 64 + lane];
                acc[b] = __builtin_amdgcn_mfma_f32_16x16x32_bf16(Af, Bf, acc[b], 0, 0, 0);
            }
            // ---- fold (linear in partial sums) ----
            f32x4 t0 = acc[0] + acc[1] + acc[2];
            f32x4 t1 = acc[1] - acc[2] - acc[3];
            if (a == 0) { Yp[0][0] += t0; Yp[0][1] += t1; }
            if (a == 1) { Yp[0][0] += t0; Yp[0][1] += t1;
                          Yp[1][0] += t0; Yp[1][1] += t1; }
            if (a == 2) { Yp[0][0] += t0; Yp[0][1] += t1;
                          Yp[1][0] -= t0; Yp[1][1] -= t1; }
            if (a == 3) { Yp[1][0] -= t0; Yp[1][1] -= t1; }
        }
        __syncthreads();
    }

    // ---- store: each wave stages its 16 finished planes (no merge needed),
    //      then plane-contiguous copy-out (504 B row chunks) ----
    float* Ys = reinterpret_cast<float*>(smem);
    {
        const int plane = kq2 * 16 + kl;
        #pragma unroll
        for (int r = 0; r < 4; ++r) {
            const int uu = mt * 16 + 4 * g4 + r;
            if (uu < T_TILES) {
                #pragma unroll
                for (int p = 0; p < 2; ++p)
                    *reinterpret_cast<float2*>(Ys + plane * YSTRIDE + p * 126 + 2 * uu)
                        = make_float2(Yp[p][0][r], Yp[p][1][r]);
            }
        }
    }
    __syncthreads();

    // copy out: 32 planes x 2 rows x 63 float2; 4096 units / 512 thr = 8 each
    #pragma unroll
    for (int i = 0; i < 8; ++i) {
        const int unit  = tid + 512 * i;        // 0..4095
        const int plane = unit >> 7;            // 0..31
        const int sub   = unit & 127;
        const int row   = sub >> 6;             // 0..1
        const int c2    = sub & 63;
        if (c2 < 63) {
            float2 v = *reinterpret_cast<const float2*>(
                Ys + plane * YSTRIDE + row * 126 + 2 * c2);
            *reinterpret_cast<float2*>(
                Y + ((size_t)(n * 64 + kh * 32 + plane)) * (OW * OW)
                  + (size_t)(2 * tb + row) * OW + 2 * c2) = v;
        }
    }
}

extern "C" void kernel_launch(void* const* d_in, const int* in_sizes, int n_in,
                              void* d_out, int out_size, void* d_ws, size_t ws_size,
                              hipStream_t stream) {
    const float* x    = (const float*)d_in[0];
    const float* filt = (const float*)d_in[1];
    float* Y = (float*)d_out;
    unsigned short* Uf = (unsigned short*)d_ws;    // 128 KB bf16 U fragments

    filter_transform<<<16, 256, 0, stream>>>(filt, Uf);

    winograd_main<<<dim3(1008), 512, 0, stream>>>(x, Uf, Y);
}

// Round 17
// 38.640 us; speedup vs baseline: 1.4486x; 1.0113x over previous
//
#include <hip/hip_runtime.h>
#include <hip/hip_bf16.h>

// Winograd F(2x2,3x3) via bf16 MFMA.
// x (8,64,128,128) f32, filt (64,64,3,3) f32 -> Y (8,64,126,126) f32
// Block = (n, ONE tt row, all 63 uu, ALL 64 k, ALL 64 c). 1024 thr = 16 waves.
// Grid 504 = 8 n x 63 tt; blockIdx&7 = n -> image pinned to one XCD.
// 2 passes (a-pairs); per pass transform ALL 64 c ONCE into 8 ab-planes
// (width 64 c', VSTRIDE 136 B) -> transform VALU and x-loads HALVE vs R16.
// Wave = (mt 4, kq 4): Yp=[2][2]=16 regs (R16's recipe for VGPR<=64 tier);
// 16 MFMA/wave/pass (2 aa x 4 b x 2 ck, K=32 each over c-halves).
// LDS 69.6 KB dynamic -> 2 blocks/CU = 32 waves/CU if VGPR<=64.
// No min-waves bound (R10/R11: coercion -> spill).

#define T_TILES 63
#define HW 128
#define OW 126

typedef __attribute__((ext_vector_type(8))) short short8;   // 8 bf16
typedef __attribute__((ext_vector_type(4))) float f32x4;

static __device__ __forceinline__ unsigned int f2bf(float f) {
    unsigned int u = __float_as_uint(f);
    return (u + 0x7FFFu + ((u >> 16) & 1u)) >> 16;   // RNE bf16
}

static __device__ __forceinline__ unsigned int pkbf2(float lo, float hi) {
    __hip_bfloat162 t;
    t.x = __float2bfloat16(lo);
    t.y = __float2bfloat16(hi);
    unsigned int r;
    __builtin_memcpy(&r, &t, 4);
    return r;                                   // v_cvt_pk_bf16_f32
}

// U_frag layout (unchanged): frag[(ab*2+ck)*4+kq][lane 0..63][j 0..7] bf16 (128 KB)
// B-operand lane l holds B[c'=(l>>4)*8+j (+32*ck)][k=(l&15)+16*kq]
__global__ __launch_bounds__(256)
void filter_transform(const float* __restrict__ g, unsigned short* __restrict__ Uf) {
    int idx = blockIdx.x * 256 + threadIdx.x;   // k*64 + c
    if (idx >= 64 * 64) return;
    int k = idx >> 6, c = idx & 63;
    const float* gp = g + idx * 9;
    float g00 = gp[0], g01 = gp[1], g02 = gp[2];
    float g10 = gp[3], g11 = gp[4], g12 = gp[5];
    float g20 = gp[6], g21 = gp[7], g22 = gp[8];
    float w[4][3];
    w[0][0] = g00;                w[0][1] = g01;                w[0][2] = g02;
    w[1][0] = 0.5f*(g00+g10+g20); w[1][1] = 0.5f*(g01+g11+g21); w[1][2] = 0.5f*(g02+g12+g22);
    w[2][0] = 0.5f*(g00-g10+g20); w[2][1] = 0.5f*(g01-g11+g21); w[2][2] = 0.5f*(g02-g12+g22);
    w[3][0] = g20;                w[3][1] = g21;                w[3][2] = g22;

    int kq = k >> 4, kl = k & 15;
    int ck = c >> 5;
    int lane = kl + (((c & 31) >> 3) << 4);
    int j = c & 7;
    #pragma unroll
    for (int a = 0; a < 4; ++a) {
        float uv[4];
        uv[0] = w[a][0];
        uv[1] = 0.5f * (w[a][0] + w[a][1] + w[a][2]);
        uv[2] = 0.5f * (w[a][0] - w[a][1] + w[a][2]);
        uv[3] = w[a][2];
        #pragma unroll
        for (int b = 0; b < 4; ++b) {
            int ab = a * 4 + b;
            size_t off = ((size_t)((ab * 2 + ck) * 4 + kq) * 64 + lane) * 8 + j;
            Uf[off] = (unsigned short)f2bf(uv[b]);
        }
    }
}

#define VSTRIDE 136                   // bytes per tm row (128 data + 8 pad; 34 words)
#define VPLANE  (64 * VSTRIDE)        // 8704 B per ab-plane; 8 planes = 69632 B
#define YSTRIDE 254                   // f32 words per k-plane in staging (252 + 2)

__global__ __launch_bounds__(1024)
void winograd_main(const float* __restrict__ x, const unsigned short* __restrict__ Uf,
                   float* __restrict__ Y) {
    extern __shared__ __align__(16) char smem[];

    const int tid  = threadIdx.x;
    const int lane = tid & 63;
    const int wv   = tid >> 6;                 // 0..15

    const int n  = blockIdx.x & 7;             // XCD pin
    const int tb = blockIdx.x >> 3;            // 0..62 (tt row)

    const int mt = wv >> 2;                    // 0..3 M-tile (16 uu each)
    const int kq = wv & 3;                     // k-quarter

    const int kl = lane & 15;
    const int g4 = lane >> 4;

    f32x4 Yp[2][2];                             // [p][q] -- 16 VGPRs
    #pragma unroll
    for (int p = 0; p < 2; ++p)
        #pragma unroll
        for (int q = 0; q < 2; ++q)
            Yp[p][q] = (f32x4){0.f, 0.f, 0.f, 0.f};

    // transform mapping: tm = uu tile (0..63; 63 = pad -> clamp addr, output
    // lands in discarded C row 63), cg = c-group of 4 channels (0..15)
    const int tm  = tid & 63;
    const int cg  = tid >> 6;
    const int tmc = (tm < T_TILES) ? tm : 0;

    // A-fragment read base (within an ab plane); + ck*64 per K-half
    const int tmA   = mt * 16 + kl;
    const int abyte = tmA * VSTRIDE + g4 * 16;

    const short8* UfV = (const short8*)Uf;

    #pragma unroll 1
    for (int P = 0; P < 2; ++P) {               // a-pair: a in {2P, 2P+1}
        const int xrow0 = 2 * tb + P;           // rows xrow0..xrow0+2 (max 127)

        // ---- transform: 8 ab planes, 64 tm x 64 c' (4 c/thread) ----
        #pragma unroll
        for (int hp = 0; hp < 2; ++hp) {
            float vv[2][8];
            #pragma unroll
            for (int hh = 0; hh < 2; ++hh) {
                const int c = cg * 4 + hp * 2 + hh;
                const float* xp = x + (((size_t)(n * 64 + c)) * HW + xrow0) * HW + 2 * tmc;
                float ld[3][4];
                #pragma unroll
                for (int rr = 0; rr < 3; ++rr) {
                    float2 lo = *reinterpret_cast<const float2*>(xp + rr * HW);
                    float2 hi = *reinterpret_cast<const float2*>(xp + rr * HW + 2);
                    ld[rr][0] = lo.x; ld[rr][1] = lo.y;
                    ld[rr][2] = hi.x; ld[rr][3] = hi.y;
                }
                float wa[2][4];
                #pragma unroll
                for (int j = 0; j < 4; ++j) {
                    if (P == 0) {
                        wa[0][j] = ld[0][j] - ld[2][j];   // a=0
                        wa[1][j] = ld[1][j] + ld[2][j];   // a=1
                    } else {
                        wa[0][j] = ld[1][j] - ld[0][j];   // a=2
                        wa[1][j] = ld[0][j] - ld[2][j];   // a=3
                    }
                }
                #pragma unroll
                for (int al = 0; al < 2; ++al) {
                    vv[hh][al*4+0] = wa[al][0] - wa[al][2];
                    vv[hh][al*4+1] = wa[al][1] + wa[al][2];
                    vv[hh][al*4+2] = wa[al][2] - wa[al][1];
                    vv[hh][al*4+3] = wa[al][1] - wa[al][3];
                }
            }
            const int wb = tm * VSTRIDE + cg * 8 + hp * 4;
            #pragma unroll
            for (int e = 0; e < 8; ++e)
                *reinterpret_cast<unsigned int*>(smem + e * VPLANE + wb) =
                    pkbf2(vv[0][e], vv[1][e]);
        }
        __syncthreads();

        // ---- GEMM: wave (mt, kq): BOTH a of the pair, 4 b, K=64 (2 ck) ----
        #pragma unroll
        for (int aa = 0; aa < 2; ++aa) {
            const int a = 2 * P + aa;
            f32x4 acc[4];
            #pragma unroll
            for (int b = 0; b < 4; ++b) acc[b] = (f32x4){0.f, 0.f, 0.f, 0.f};
            #pragma unroll
            for (int b = 0; b < 4; ++b) {
                #pragma unroll
                for (int ck = 0; ck < 2; ++ck) {
                    const char* ap = smem + (aa * 4 + b) * VPLANE + abyte + ck * 64;
                    uint2 q0 = *reinterpret_cast<const uint2*>(ap);
                    uint2 q1 = *reinterpret_cast<const uint2*>(ap + 8);
                    uint4 t; t.x = q0.x; t.y = q0.y; t.z = q1.x; t.w = q1.y;
                    short8 Af = *reinterpret_cast<short8*>(&t);
                    short8 Bf = UfV[(size_t)(((a * 4 + b) * 2 + ck) * 4 + kq) * 64 + lane];
                    acc[b] = __builtin_amdgcn_mfma_f32_16x16x32_bf16(Af, Bf, acc[b], 0, 0, 0);
                }
            }
            // ---- fold (linear in partial sums) ----
            f32x4 t0 = acc[0] + acc[1] + acc[2];
            f32x4 t1 = acc[1] - acc[2] - acc[3];
            if (a == 0) { Yp[0][0] += t0; Yp[0][1] += t1; }
            if (a == 1) { Yp[0][0] += t0; Yp[0][1] += t1;
                          Yp[1][0] += t0; Yp[1][1] += t1; }
            if (a == 2) { Yp[0][0] += t0; Yp[0][1] += t1;
                          Yp[1][0] -= t0; Yp[1][1] -= t1; }
            if (a == 3) { Yp[1][0] -= t0; Yp[1][1] -= t1; }
        }
        __syncthreads();
    }

    // ---- store: each wave stages its 16 finished planes (no merge),
    //      then plane-contiguous copy-out (504 B row chunks) ----
    float* Ys = reinterpret_cast<float*>(smem);
    {
        const int plane = kq * 16 + kl;         // = k (0..63)
        #pragma unroll
        for (int r = 0; r < 4; ++r) {
            const int uu = mt * 16 + 4 * g4 + r;
            if (uu < T_TILES) {
                #pragma unroll
                for (int p = 0; p < 2; ++p)
                    *reinterpret_cast<float2*>(Ys + plane * YSTRIDE + p * 126 + 2 * uu)
                        = make_float2(Yp[p][0][r], Yp[p][1][r]);
            }
        }
    }
    __syncthreads();

    // copy out: 64 planes x 2 rows x 63 float2 = 8064 units / 1024 thr = 8 each
    #pragma unroll
    for (int i = 0; i < 8; ++i) {
        const int unit  = tid + 1024 * i;       // 0..8191
        const int plane = unit >> 7;            // 0..63
        const int sub   = unit & 127;
        const int row   = sub >> 6;             // 0..1
        const int c2    = sub & 63;
        if (c2 < 63) {
            float2 v = *reinterpret_cast<const float2*>(
                Ys + plane * YSTRIDE + row * 126 + 2 * c2);
            *reinterpret_cast<float2*>(
                Y + ((size_t)(n * 64 + plane)) * (OW * OW)
                  + (size_t)(2 * tb + row) * OW + 2 * c2) = v;
        }
    }
}

extern "C" void kernel_launch(void* const* d_in, const int* in_sizes, int n_in,
                              void* d_out, int out_size, void* d_ws, size_t ws_size,
                              hipStream_t stream) {
    const float* x    = (const float*)d_in[0];
    const float* filt = (const float*)d_in[1];
    float* Y = (float*)d_out;
    unsigned short* Uf = (unsigned short*)d_ws;    // 128 KB bf16 U fragments

    filter_transform<<<16, 256, 0, stream>>>(filt, Uf);

    winograd_main<<<dim3(504), 1024, 8 * VPLANE, stream>>>(x, Uf, Y);
}

// Round 18
// 36.725 us; speedup vs baseline: 1.5241x; 1.0522x over previous
//
#include <hip/hip_runtime.h>
#include <hip/hip_bf16.h>

// Winograd F(2x2,3x3) via bf16 MFMA.
// x (8,64,128,128) f32, filt (64,64,3,3) f32 -> Y (8,64,126,126) f32
// Block = (n, ONE tt row, all 63 uu, ALL 64 k, ALL 64 c). 1024 thr = 16 waves.
// Grid 504 = 8 n x 63 tt; blockIdx&7 = n -> image pinned to one XCD.
// 4 half-passes (2 a-pairs x 2 c-halves), DOUBLE-BUFFERED V (2 x 36.9 KB):
//   transform(p+1) and GEMM(p) share one barrier window -> VALU/MFMA pipes
//   overlap wave-level (R17 post-mortem: phase-serialization was the stall).
// Wave = (mt 4, kq 4); Yp=[2][2]=16 regs (VGPR<=64 tier -- R15/R16 lesson).
// No min-waves bound (R10/R11: coercion -> spill).

#define T_TILES 63
#define HW 128
#define OW 126

typedef __attribute__((ext_vector_type(8))) short short8;   // 8 bf16
typedef __attribute__((ext_vector_type(4))) float f32x4;

static __device__ __forceinline__ unsigned int f2bf(float f) {
    unsigned int u = __float_as_uint(f);
    return (u + 0x7FFFu + ((u >> 16) & 1u)) >> 16;   // RNE bf16
}

static __device__ __forceinline__ unsigned int pkbf2(float lo, float hi) {
    __hip_bfloat162 t;
    t.x = __float2bfloat16(lo);
    t.y = __float2bfloat16(hi);
    unsigned int r;
    __builtin_memcpy(&r, &t, 4);
    return r;                                   // v_cvt_pk_bf16_f32
}

// U_frag layout (unchanged): frag[(ab*2+ck)*4+kq][lane 0..63][j 0..7] bf16 (128 KB)
// B-operand lane l holds B[c'=(l>>4)*8+j (+32*ck)][k=(l&15)+16*kq]
__global__ __launch_bounds__(256)
void filter_transform(const float* __restrict__ g, unsigned short* __restrict__ Uf) {
    int idx = blockIdx.x * 256 + threadIdx.x;   // k*64 + c
    if (idx >= 64 * 64) return;
    int k = idx >> 6, c = idx & 63;
    const float* gp = g + idx * 9;
    float g00 = gp[0], g01 = gp[1], g02 = gp[2];
    float g10 = gp[3], g11 = gp[4], g12 = gp[5];
    float g20 = gp[6], g21 = gp[7], g22 = gp[8];
    float w[4][3];
    w[0][0] = g00;                w[0][1] = g01;                w[0][2] = g02;
    w[1][0] = 0.5f*(g00+g10+g20); w[1][1] = 0.5f*(g01+g11+g21); w[1][2] = 0.5f*(g02+g12+g22);
    w[2][0] = 0.5f*(g00-g10+g20); w[2][1] = 0.5f*(g01-g11+g21); w[2][2] = 0.5f*(g02-g12+g22);
    w[3][0] = g20;                w[3][1] = g21;                w[3][2] = g22;

    int kq = k >> 4, kl = k & 15;
    int ck = c >> 5;
    int lane = kl + (((c & 31) >> 3) << 4);
    int j = c & 7;
    #pragma unroll
    for (int a = 0; a < 4; ++a) {
        float uv[4];
        uv[0] = w[a][0];
        uv[1] = 0.5f * (w[a][0] + w[a][1] + w[a][2]);
        uv[2] = 0.5f * (w[a][0] - w[a][1] + w[a][2]);
        uv[3] = w[a][2];
        #pragma unroll
        for (int b = 0; b < 4; ++b) {
            int ab = a * 4 + b;
            size_t off = ((size_t)((ab * 2 + ck) * 4 + kq) * 64 + lane) * 8 + j;
            Uf[off] = (unsigned short)f2bf(uv[b]);
        }
    }
}

#define VSTRIDE 72                    // bytes per tm row (64 data + 8 pad)
#define VPLANE  (64 * VSTRIDE)        // 4608 B per ab-plane
#define VBUF    (8 * VPLANE)          // 36864 B per buffer; 2 buffers = 73728 B
#define YSTRIDE 254                   // f32 words per k-plane in staging (252 + 2)

__global__ __launch_bounds__(1024)
void winograd_main(const float* __restrict__ x, const unsigned short* __restrict__ Uf,
                   float* __restrict__ Y) {
    extern __shared__ __align__(16) char smem[];

    const int tid  = threadIdx.x;
    const int lane = tid & 63;
    const int wv   = tid >> 6;                 // 0..15

    const int n  = blockIdx.x & 7;             // XCD pin
    const int tb = blockIdx.x >> 3;            // 0..62 (tt row)

    const int mt = wv >> 2;                    // 0..3 M-tile (16 uu each)
    const int kq = wv & 3;                     // k-quarter

    const int kl = lane & 15;
    const int g4 = lane >> 4;

    f32x4 Yp[2][2];                             // [p][q] -- 16 VGPRs
    #pragma unroll
    for (int p = 0; p < 2; ++p)
        #pragma unroll
        for (int q = 0; q < 2; ++q)
            Yp[p][q] = (f32x4){0.f, 0.f, 0.f, 0.f};

    // transform mapping: tm = uu tile (0..63; 63 = pad -> clamp addr, output
    // lands in discarded C row 63), cg = c-pair group (0..15): 2 channels/thread
    const int tm  = tid & 63;
    const int cg  = tid >> 6;
    const int tmc = (tm < T_TILES) ? tm : 0;

    // A-fragment read base (within an ab plane)
    const int tmA   = mt * 16 + kl;
    const int abyte = tmA * VSTRIDE + g4 * 16;

    const short8* UfV = (const short8*)Uf;

    // ---- transform one half-pass hp = (P, ck) into buffer bufSel ----
    auto TRANSFORM = [&](int hp, int bufSel) {
        const int P  = hp >> 1;
        const int ck = hp & 1;
        const int xrow0 = 2 * tb + P;           // rows xrow0..xrow0+2 (max 127)
        float vv[2][8];
        #pragma unroll
        for (int hh = 0; hh < 2; ++hh) {
            const int c = ck * 32 + cg * 2 + hh;
            const float* xp = x + (((size_t)(n * 64 + c)) * HW + xrow0) * HW + 2 * tmc;
            float ld[3][4];
            #pragma unroll
            for (int rr = 0; rr < 3; ++rr) {
                float2 lo = *reinterpret_cast<const float2*>(xp + rr * HW);
                float2 hi = *reinterpret_cast<const float2*>(xp + rr * HW + 2);
                ld[rr][0] = lo.x; ld[rr][1] = lo.y;
                ld[rr][2] = hi.x; ld[rr][3] = hi.y;
            }
            float wa[2][4];
            #pragma unroll
            for (int j = 0; j < 4; ++j) {
                if (P == 0) {
                    wa[0][j] = ld[0][j] - ld[2][j];   // a=0
                    wa[1][j] = ld[1][j] + ld[2][j];   // a=1
                } else {
                    wa[0][j] = ld[1][j] - ld[0][j];   // a=2
                    wa[1][j] = ld[0][j] - ld[2][j];   // a=3
                }
            }
            #pragma unroll
            for (int al = 0; al < 2; ++al) {
                vv[hh][al*4+0] = wa[al][0] - wa[al][2];
                vv[hh][al*4+1] = wa[al][1] + wa[al][2];
                vv[hh][al*4+2] = wa[al][2] - wa[al][1];
                vv[hh][al*4+3] = wa[al][1] - wa[al][3];
            }
        }
        const int wb = bufSel * VBUF + tm * VSTRIDE + cg * 4;
        #pragma unroll
        for (int e = 0; e < 8; ++e)
            *reinterpret_cast<unsigned int*>(smem + e * VPLANE + wb) =
                pkbf2(vv[0][e], vv[1][e]);
    };

    // ---- pipeline: one barrier per half-pass; transform(p+1) || GEMM(p) ----
    TRANSFORM(0, 0);
    __syncthreads();

    #pragma unroll 1
    for (int p = 0; p < 4; ++p) {
        if (p < 3) TRANSFORM(p + 1, (p + 1) & 1);

        const int P  = p >> 1;
        const int ck = p & 1;
        const int bb = (p & 1) * VBUF;
        #pragma unroll
        for (int aa = 0; aa < 2; ++aa) {
            const int a = 2 * P + aa;
            f32x4 acc[4];
            #pragma unroll
            for (int b = 0; b < 4; ++b) acc[b] = (f32x4){0.f, 0.f, 0.f, 0.f};
            #pragma unroll
            for (int b = 0; b < 4; ++b) {
                const char* ap = smem + bb + (aa * 4 + b) * VPLANE + abyte;
                uint2 q0 = *reinterpret_cast<const uint2*>(ap);
                uint2 q1 = *reinterpret_cast<const uint2*>(ap + 8);
                uint4 t; t.x = q0.x; t.y = q0.y; t.z = q1.x; t.w = q1.y;
                short8 Af = *reinterpret_cast<short8*>(&t);
                short8 Bf = UfV[(size_t)(((a * 4 + b) * 2 + ck) * 4 + kq) * 64 + lane];
                acc[b] = __builtin_amdgcn_mfma_f32_16x16x32_bf16(Af, Bf, acc[b], 0, 0, 0);
            }
            // fold (linear in partial sums; ck halves accumulate)
            f32x4 t0 = acc[0] + acc[1] + acc[2];
            f32x4 t1 = acc[1] - acc[2] - acc[3];
            if (a == 0) { Yp[0][0] += t0; Yp[0][1] += t1; }
            if (a == 1) { Yp[0][0] += t0; Yp[0][1] += t1;
                          Yp[1][0] += t0; Yp[1][1] += t1; }
            if (a == 2) { Yp[0][0] += t0; Yp[0][1] += t1;
                          Yp[1][0] -= t0; Yp[1][1] -= t1; }
            if (a == 3) { Yp[1][0] -= t0; Yp[1][1] -= t1; }
        }
        __syncthreads();
    }

    // ---- store: each wave stages its 16 finished planes (no merge),
    //      then plane-contiguous copy-out (504 B row chunks) ----
    float* Ys = reinterpret_cast<float*>(smem);
    {
        const int plane = kq * 16 + kl;         // = k (0..63)
        #pragma unroll
        for (int r = 0; r < 4; ++r) {
            const int uu = mt * 16 + 4 * g4 + r;
            if (uu < T_TILES) {
                #pragma unroll
                for (int p = 0; p < 2; ++p)
                    *reinterpret_cast<float2*>(Ys + plane * YSTRIDE + p * 126 + 2 * uu)
                        = make_float2(Yp[p][0][r], Yp[p][1][r]);
            }
        }
    }
    __syncthreads();

    // copy out: 64 planes x 2 rows x 63 float2 = 8064 units / 1024 thr = 8 each
    #pragma unroll
    for (int i = 0; i < 8; ++i) {
        const int unit  = tid + 1024 * i;       // 0..8191
        const int plane = unit >> 7;            // 0..63
        const int sub   = unit & 127;
        const int row   = sub >> 6;             // 0..1
        const int c2    = sub & 63;
        if (c2 < 63) {
            float2 v = *reinterpret_cast<const float2*>(
                Ys + plane * YSTRIDE + row * 126 + 2 * c2);
            *reinterpret_cast<float2*>(
                Y + ((size_t)(n * 64 + plane)) * (OW * OW)
                  + (size_t)(2 * tb + row) * OW + 2 * c2) = v;
        }
    }
}

extern "C" void kernel_launch(void* const* d_in, const int* in_sizes, int n_in,
                              void* d_out, int out_size, void* d_ws, size_t ws_size,
                              hipStream_t stream) {
    const float* x    = (const float*)d_in[0];
    const float* filt = (const float*)d_in[1];
    float* Y = (float*)d_out;
    unsigned short* Uf = (unsigned short*)d_ws;    // 128 KB bf16 U fragments

    filter_transform<<<16, 256, 0, stream>>>(filt, Uf);

    winograd_main<<<dim3(504), 1024, 2 * VBUF, stream>>>(x, Uf, Y);
}

// Round 19
// 31.802 us; speedup vs baseline: 1.7601x; 1.1548x over previous
//
#include <hip/hip_runtime.h>
#include <hip/hip_bf16.h>

// Winograd F(2x2,3x3) via bf16 MFMA.
// x (8,64,128,128) f32, filt (64,64,3,3) f32 -> Y (8,64,126,126) f32
// Block = (n, ONE tt row, uu-HALF: 32 tiles, ALL 64 k, ALL 64 c). 512 thr = 8 waves.
// Grid 1008 = 8 n x 63 tt x 2 uuh; blockIdx&7 = n -> image pinned to one XCD.
// 4 half-passes (2 a-pairs x 2 c-halves), DOUBLE-BUFFERED V (2 x 18.4 KB):
//   transform(p+1) || GEMM(p) per barrier window (R18 structure), but the
//   barrier domain is 8 waves and 4 independent blocks/CU fill each other's
//   load-burst bubbles (R18 post-mortem: 16-wave correlated stalls).
// Wave = (mt 2, kq 4); Yp=[2][2]=16 regs (VGPR<=64 tier -- R15/R16 lesson).
// No min-waves bound (R10/R11: coercion -> spill).

#define T_TILES 63
#define HW 128
#define OW 126

typedef __attribute__((ext_vector_type(8))) short short8;   // 8 bf16
typedef __attribute__((ext_vector_type(4))) float f32x4;

static __device__ __forceinline__ unsigned int f2bf(float f) {
    unsigned int u = __float_as_uint(f);
    return (u + 0x7FFFu + ((u >> 16) & 1u)) >> 16;   // RNE bf16
}

static __device__ __forceinline__ unsigned int pkbf2(float lo, float hi) {
    __hip_bfloat162 t;
    t.x = __float2bfloat16(lo);
    t.y = __float2bfloat16(hi);
    unsigned int r;
    __builtin_memcpy(&r, &t, 4);
    return r;                                   // v_cvt_pk_bf16_f32
}

// U_frag layout (unchanged): frag[(ab*2+ck)*4+kq][lane 0..63][j 0..7] bf16 (128 KB)
// B-operand lane l holds B[c'=(l>>4)*8+j (+32*ck)][k=(l&15)+16*kq]
__global__ __launch_bounds__(256)
void filter_transform(const float* __restrict__ g, unsigned short* __restrict__ Uf) {
    int idx = blockIdx.x * 256 + threadIdx.x;   // k*64 + c
    if (idx >= 64 * 64) return;
    int k = idx >> 6, c = idx & 63;
    const float* gp = g + idx * 9;
    float g00 = gp[0], g01 = gp[1], g02 = gp[2];
    float g10 = gp[3], g11 = gp[4], g12 = gp[5];
    float g20 = gp[6], g21 = gp[7], g22 = gp[8];
    float w[4][3];
    w[0][0] = g00;                w[0][1] = g01;                w[0][2] = g02;
    w[1][0] = 0.5f*(g00+g10+g20); w[1][1] = 0.5f*(g01+g11+g21); w[1][2] = 0.5f*(g02+g12+g22);
    w[2][0] = 0.5f*(g00-g10+g20); w[2][1] = 0.5f*(g01-g11+g21); w[2][2] = 0.5f*(g02-g12+g22);
    w[3][0] = g20;                w[3][1] = g21;                w[3][2] = g22;

    int kq = k >> 4, kl = k & 15;
    int ck = c >> 5;
    int lane = kl + (((c & 31) >> 3) << 4);
    int j = c & 7;
    #pragma unroll
    for (int a = 0; a < 4; ++a) {
        float uv[4];
        uv[0] = w[a][0];
        uv[1] = 0.5f * (w[a][0] + w[a][1] + w[a][2]);
        uv[2] = 0.5f * (w[a][0] - w[a][1] + w[a][2]);
        uv[3] = w[a][2];
        #pragma unroll
        for (int b = 0; b < 4; ++b) {
            int ab = a * 4 + b;
            size_t off = ((size_t)((ab * 2 + ck) * 4 + kq) * 64 + lane) * 8 + j;
            Uf[off] = (unsigned short)f2bf(uv[b]);
        }
    }
}

#define VSTRIDE 72                    // bytes per tm row (64 data + 8 pad)
#define VPLANE  (32 * VSTRIDE)        // 2304 B per ab-plane (32 tiles)
#define VBUF    (8 * VPLANE)          // 18432 B per buffer; 2 buffers = 36864 B
#define YSTRIDE 130                   // f32 words per k-plane staging (2x64 + 2 pad)

__global__ __launch_bounds__(512)
void winograd_main(const float* __restrict__ x, const unsigned short* __restrict__ Uf,
                   float* __restrict__ Y) {
    __shared__ __align__(16) char smem[2 * VBUF];   // 36864 B -> 4 blocks/CU

    const int tid  = threadIdx.x;
    const int lane = tid & 63;
    const int wv   = tid >> 6;                 // 0..7

    const int n   = blockIdx.x & 7;            // XCD pin
    const int r2  = blockIdx.x >> 3;           // 0..125
    const int uuh = r2 & 1;                    // uu half
    const int tb  = r2 >> 1;                   // 0..62 (tt row)

    const int mt = wv >> 2;                    // 0..1 M-tile (16 uu each)
    const int kq = wv & 3;                     // k-quarter

    const int kl = lane & 15;
    const int g4 = lane >> 4;

    f32x4 Yp[2][2];                             // [p][q] -- 16 VGPRs
    #pragma unroll
    for (int p = 0; p < 2; ++p)
        #pragma unroll
        for (int q = 0; q < 2; ++q)
            Yp[p][q] = (f32x4){0.f, 0.f, 0.f, 0.f};

    // transform mapping: tm_loc = local uu tile (0..31), cg = c-pair group (0..15).
    // uu_g==63 (uuh=1, tm_loc=31) is padding: clamp addr; discarded in epilogue.
    const int tm_loc = tid & 31;
    const int cg     = tid >> 5;
    const int uu_g   = uuh * 32 + tm_loc;
    const int tmcg   = (uu_g < T_TILES) ? uu_g : 0;

    // A-fragment read base (within an ab plane)
    const int tmA   = mt * 16 + kl;            // 0..31
    const int abyte = tmA * VSTRIDE + g4 * 16;

    const short8* UfV = (const short8*)Uf;

    // ---- transform one half-pass hp = (P, ck) into buffer bufSel ----
    auto TRANSFORM = [&](int hp, int bufSel) {
        const int P  = hp >> 1;
        const int ck = hp & 1;
        const int xrow0 = 2 * tb + P;           // rows xrow0..xrow0+2 (max 127)
        float vv[2][8];
        #pragma unroll
        for (int hh = 0; hh < 2; ++hh) {
            const int c = ck * 32 + cg * 2 + hh;
            const float* xp = x + (((size_t)(n * 64 + c)) * HW + xrow0) * HW + 2 * tmcg;
            float ld[3][4];
            #pragma unroll
            for (int rr = 0; rr < 3; ++rr) {
                float2 lo = *reinterpret_cast<const float2*>(xp + rr * HW);
                float2 hi = *reinterpret_cast<const float2*>(xp + rr * HW + 2);
                ld[rr][0] = lo.x; ld[rr][1] = lo.y;
                ld[rr][2] = hi.x; ld[rr][3] = hi.y;
            }
            float wa[2][4];
            #pragma unroll
            for (int j = 0; j < 4; ++j) {
                if (P == 0) {
                    wa[0][j] = ld[0][j] - ld[2][j];   // a=0
                    wa[1][j] = ld[1][j] + ld[2][j];   // a=1
                } else {
                    wa[0][j] = ld[1][j] - ld[0][j];   // a=2
                    wa[1][j] = ld[0][j] - ld[2][j];   // a=3
                }
            }
            #pragma unroll
            for (int al = 0; al < 2; ++al) {
                vv[hh][al*4+0] = wa[al][0] - wa[al][2];
                vv[hh][al*4+1] = wa[al][1] + wa[al][2];
                vv[hh][al*4+2] = wa[al][2] - wa[al][1];
                vv[hh][al*4+3] = wa[al][1] - wa[al][3];
            }
        }
        const int wb = bufSel * VBUF + tm_loc * VSTRIDE + cg * 4;
        #pragma unroll
        for (int e = 0; e < 8; ++e)
            *reinterpret_cast<unsigned int*>(smem + e * VPLANE + wb) =
                pkbf2(vv[0][e], vv[1][e]);
    };

    // ---- pipeline: one barrier per half-pass; transform(p+1) || GEMM(p) ----
    TRANSFORM(0, 0);
    __syncthreads();

    #pragma unroll 1
    for (int p = 0; p < 4; ++p) {
        if (p < 3) TRANSFORM(p + 1, (p + 1) & 1);

        const int P  = p >> 1;
        const int ck = p & 1;
        const int bb = (p & 1) * VBUF;
        #pragma unroll
        for (int aa = 0; aa < 2; ++aa) {
            const int a = 2 * P + aa;
            f32x4 acc[4];
            #pragma unroll
            for (int b = 0; b < 4; ++b) acc[b] = (f32x4){0.f, 0.f, 0.f, 0.f};
            #pragma unroll
            for (int b = 0; b < 4; ++b) {
                const char* ap = smem + bb + (aa * 4 + b) * VPLANE + abyte;
                uint2 q0 = *reinterpret_cast<const uint2*>(ap);
                uint2 q1 = *reinterpret_cast<const uint2*>(ap + 8);
                uint4 t; t.x = q0.x; t.y = q0.y; t.z = q1.x; t.w = q1.y;
                short8 Af = *reinterpret_cast<short8*>(&t);
                short8 Bf = UfV[(size_t)(((a * 4 + b) * 2 + ck) * 4 + kq) * 64 + lane];
                acc[b] = __builtin_amdgcn_mfma_f32_16x16x32_bf16(Af, Bf, acc[b], 0, 0, 0);
            }
            // fold (linear in partial sums; ck halves accumulate)
            f32x4 t0 = acc[0] + acc[1] + acc[2];
            f32x4 t1 = acc[1] - acc[2] - acc[3];
            if (a == 0) { Yp[0][0] += t0; Yp[0][1] += t1; }
            if (a == 1) { Yp[0][0] += t0; Yp[0][1] += t1;
                          Yp[1][0] += t0; Yp[1][1] += t1; }
            if (a == 2) { Yp[0][0] += t0; Yp[0][1] += t1;
                          Yp[1][0] -= t0; Yp[1][1] -= t1; }
            if (a == 3) { Yp[1][0] -= t0; Yp[1][1] -= t1; }
        }
        __syncthreads();
    }

    // ---- store: each wave stages its 16 finished planes (no merge),
    //      then plane-contiguous copy-out (256 B row chunks) ----
    float* Ys = reinterpret_cast<float*>(smem);
    {
        const int plane = kq * 16 + kl;         // = k (0..63)
        #pragma unroll
        for (int r = 0; r < 4; ++r) {
            const int uu_loc = mt * 16 + 4 * g4 + r;   // 0..31
            if (uuh * 32 + uu_loc < T_TILES) {
                #pragma unroll
                for (int p = 0; p < 2; ++p)
                    *reinterpret_cast<float2*>(Ys + plane * YSTRIDE + p * 64 + 2 * uu_loc)
                        = make_float2(Yp[p][0][r], Yp[p][1][r]);
            }
        }
    }
    __syncthreads();

    // copy out: 64 planes x 2 rows x 32 float2 = 4096 units / 512 thr = 8 each
    #pragma unroll
    for (int i = 0; i < 8; ++i) {
        const int unit  = tid + 512 * i;        // 0..4095
        const int plane = unit >> 6;            // 0..63
        const int sub   = unit & 63;
        const int row   = sub >> 5;             // 0..1
        const int c2    = sub & 31;
        const int col_g = uuh * 64 + 2 * c2;
        if (col_g <= 124) {
            float2 v = *reinterpret_cast<const float2*>(
                Ys + plane * YSTRIDE + row * 64 + 2 * c2);
            *reinterpret_cast<float2*>(
                Y + ((size_t)(n * 64 + plane)) * (OW * OW)
                  + (size_t)(2 * tb + row) * OW + col_g) = v;
        }
    }
}

extern "C" void kernel_launch(void* const* d_in, const int* in_sizes, int n_in,
                              void* d_out, int out_size, void* d_ws, size_t ws_size,
                              hipStream_t stream) {
    const float* x    = (const float*)d_in[0];
    const float* filt = (const float*)d_in[1];
    float* Y = (float*)d_out;
    unsigned short* Uf = (unsigned short*)d_ws;    // 128 KB bf16 U fragments

    filter_transform<<<16, 256, 0, stream>>>(filt, Uf);

    winograd_main<<<dim3(1008), 512, 0, stream>>>(x, Uf, Y);
}